// Round 1
// baseline (1849.558 us; speedup 1.0000x reference)
//
#include <hip/hip_runtime.h>
#include <cstdint>
#include <cstddef>

#define GRAPH_SIZE 100
#define CH 64
#define N_GRAPHS 4096
#define N_NODES (N_GRAPHS * GRAPH_SIZE)   // 409600
#define DEG 16
#define N_EDGES (N_NODES * DEG)           // 6553600
#define BN_EPS 1e-3f

// ---------------------------------------------------------------- utilities
__global__ void zero_kernel(int* __restrict__ p, int n) {
  int i = blockIdx.x * blockDim.x + threadIdx.x;
  if (i < n) p[i] = 0;
}

// ---------------------------------------------------------------- CSR build
__global__ __launch_bounds__(256) void hist_kernel(const int* __restrict__ recv,
                                                   int* __restrict__ cnt) {
  int e = blockIdx.x * 256 + threadIdx.x;   // grid sized exactly
  atomicAdd(&cnt[recv[e]], 1);
}

// per-block exclusive scan of cnt -> off, block totals -> bsum
__global__ __launch_bounds__(256) void scan1_kernel(const int* __restrict__ cnt,
                                                    int* __restrict__ off,
                                                    int* __restrict__ bsum) {
  __shared__ int s[256];
  int tid = threadIdx.x;
  int i = blockIdx.x * 256 + tid;
  int v = cnt[i];
  s[tid] = v;
  __syncthreads();
  int sum = v;
  for (int d = 1; d < 256; d <<= 1) {
    int t = (tid >= d) ? s[tid - d] : 0;
    __syncthreads();
    sum += t;
    s[tid] = sum;
    __syncthreads();
  }
  off[i] = sum - v;                 // exclusive within block
  if (tid == 255) bsum[blockIdx.x] = sum;
}

// single-block exclusive scan of bsum[n]
__global__ __launch_bounds__(256) void scan2_kernel(int* __restrict__ bsum, int n) {
  __shared__ int s[256];
  int tid = threadIdx.x;
  int run = 0;
  for (int base = 0; base < n; base += 256) {
    int i = base + tid;
    int v = (i < n) ? bsum[i] : 0;
    s[tid] = v;
    __syncthreads();
    int sum = v;
    for (int d = 1; d < 256; d <<= 1) {
      int t = (tid >= d) ? s[tid - d] : 0;
      __syncthreads();
      sum += t;
      s[tid] = sum;
      __syncthreads();
    }
    if (i < n) bsum[i] = run + sum - v;   // exclusive global
    run += s[255];
    __syncthreads();
  }
}

__global__ __launch_bounds__(256) void scan3_kernel(int* __restrict__ off,
                                                    const int* __restrict__ bsum,
                                                    int* __restrict__ cur) {
  int i = blockIdx.x * 256 + threadIdx.x;
  int o = off[i] + bsum[blockIdx.x];
  off[i] = o;
  cur[i] = o;
}

__global__ __launch_bounds__(256) void scatter_kernel(const int* __restrict__ recv,
                                                      const int* __restrict__ send,
                                                      int* __restrict__ cur,
                                                      int* __restrict__ sorted) {
  int e = blockIdx.x * 256 + threadIdx.x;
  int r = recv[e];
  int pos = atomicAdd(&cur[r], 1);
  sorted[pos] = send[e];
}

// --------------------------------------------- aggregation + conv + BN + ELU
// one wave per node; lane = channel. W1 column held in 64 VGPRs per lane.
__global__ __launch_bounds__(256) void aggconv_kernel(
    const float* __restrict__ x, const int* __restrict__ off,
    const int* __restrict__ cnt, const int* __restrict__ sorted,
    const float* __restrict__ W1, const float* __restrict__ b1,
    const float* __restrict__ gamma, const float* __restrict__ beta,
    const float* __restrict__ bn_mean, const float* __restrict__ bn_var,
    float* __restrict__ h) {
  int lane = threadIdx.x & 63;
  int wave = threadIdx.x >> 6;
  int node = blockIdx.x * 4 + wave;

  float w[64];
#pragma unroll
  for (int i = 0; i < 64; i++) w[i] = W1[i * 64 + lane];

  int o = off[node];
  int d = cnt[node];
  float acc = 0.f;
  int k = 0;
  for (; k + 4 <= d; k += 4) {
    int s0 = sorted[o + k + 0];
    int s1 = sorted[o + k + 1];
    int s2 = sorted[o + k + 2];
    int s3 = sorted[o + k + 3];
    acc += x[s0 * 64 + lane];
    acc += x[s1 * 64 + lane];
    acc += x[s2 * 64 + lane];
    acc += x[s3 * 64 + lane];
  }
  for (; k < d; k++) {
    int s = sorted[o + k];
    acc += x[s * 64 + lane];
  }

  float hv = b1[lane];
#pragma unroll
  for (int i = 0; i < 64; i++) {
    hv = fmaf(__shfl(acc, i), w[i], hv);
  }
  // BN (inference) + ELU
  float scale = gamma[lane] * rsqrtf(bn_var[lane] + BN_EPS);
  hv = (hv - bn_mean[lane]) * scale + beta[lane];
  hv = (hv > 0.f) ? hv : expm1f(hv);
  h[node * 64 + lane] = hv;
}

// ---------------------------------------------------------------- GEMM2
// C[4096,256] = relu(A[4096,6400] @ B[6400,256] + bias)
__global__ __launch_bounds__(256) void gemm2_kernel(const float* __restrict__ A,
                                                    const float* __restrict__ B,
                                                    const float* __restrict__ bias,
                                                    float* __restrict__ C) {
  __shared__ float As[16][68];  // [k][m], padded (68*4 bytes keeps 16B align)
  __shared__ float Bs[16][68];  // [k][n]
  const int K = 6400;
  int tid = threadIdx.x;
  int tx = tid & 15;        // 0..15  -> n group
  int ty = tid >> 4;        // 0..15  -> m group
  int bm = blockIdx.x * 64;
  int bn = blockIdx.y * 64;

  float acc[4][4] = {};

  for (int k0 = 0; k0 < K; k0 += 16) {
    // A tile: rows bm+ty+16i, col k0+tx  -> As[tx][ty+16i]
#pragma unroll
    for (int i = 0; i < 4; i++)
      As[tx][ty + 16 * i] = A[(size_t)(bm + ty + 16 * i) * K + k0 + tx];
    // B tile: rows k0 + tid/64 + 4i, col bn + tid%64
#pragma unroll
    for (int i = 0; i < 4; i++)
      Bs[(tid >> 6) + 4 * i][tid & 63] = B[(size_t)(k0 + (tid >> 6) + 4 * i) * 256 + bn + (tid & 63)];
    __syncthreads();
#pragma unroll
    for (int kk = 0; kk < 16; kk++) {
      float4 a = *(const float4*)&As[kk][ty * 4];
      float4 b = *(const float4*)&Bs[kk][tx * 4];
      const float av[4] = {a.x, a.y, a.z, a.w};
      const float bv[4] = {b.x, b.y, b.z, b.w};
#pragma unroll
      for (int i = 0; i < 4; i++)
#pragma unroll
        for (int j = 0; j < 4; j++)
          acc[i][j] = fmaf(av[i], bv[j], acc[i][j]);
    }
    __syncthreads();
  }

  float4 bb = *(const float4*)&bias[bn + tx * 4];
  const float bvv[4] = {bb.x, bb.y, bb.z, bb.w};
#pragma unroll
  for (int i = 0; i < 4; i++) {
    float4 o;
    float* op = (float*)&o;
#pragma unroll
    for (int j = 0; j < 4; j++) op[j] = fmaxf(acc[i][j] + bvv[j], 0.f);
    *(float4*)&C[(size_t)(bm + ty * 4 + i) * 256 + bn + tx * 4] = o;
  }
}

// ---------------------------------------------------------------- tail
// per row: relu(in[256] @ Wd2[256,128] + bd2) @ Wd3[128] + bd3 -> sigmoid
__global__ __launch_bounds__(256) void tail_kernel(const float* __restrict__ out1,
                                                   const float* __restrict__ Wd2,
                                                   const float* __restrict__ bd2,
                                                   const float* __restrict__ Wd3,
                                                   const float* __restrict__ bd3,
                                                   float* __restrict__ out) {
  int lane = threadIdx.x & 63;
  int wave = threadIdx.x >> 6;
  int row = blockIdx.x * 4 + wave;

  const float* in = out1 + (size_t)row * 256;
  float i0 = in[lane];
  float i1 = in[64 + lane];
  float i2 = in[128 + lane];
  float i3 = in[192 + lane];

  float a0 = bd2[lane];
  float a1 = bd2[64 + lane];
#pragma unroll
  for (int i = 0; i < 64; i++) {
    float v0 = __shfl(i0, i);
    a0 = fmaf(v0, Wd2[(i)*128 + lane], a0);
    a1 = fmaf(v0, Wd2[(i)*128 + 64 + lane], a1);
    float v1 = __shfl(i1, i);
    a0 = fmaf(v1, Wd2[(64 + i) * 128 + lane], a0);
    a1 = fmaf(v1, Wd2[(64 + i) * 128 + 64 + lane], a1);
    float v2 = __shfl(i2, i);
    a0 = fmaf(v2, Wd2[(128 + i) * 128 + lane], a0);
    a1 = fmaf(v2, Wd2[(128 + i) * 128 + 64 + lane], a1);
    float v3 = __shfl(i3, i);
    a0 = fmaf(v3, Wd2[(192 + i) * 128 + lane], a0);
    a1 = fmaf(v3, Wd2[(192 + i) * 128 + 64 + lane], a1);
  }
  a0 = fmaxf(a0, 0.f);
  a1 = fmaxf(a1, 0.f);
  float p = a0 * Wd3[lane] + a1 * Wd3[64 + lane];
#pragma unroll
  for (int m = 32; m >= 1; m >>= 1) p += __shfl_xor(p, m);
  if (lane == 0) out[row] = 1.f / (1.f + expf(-(p + bd3[0])));
}

// ---------------------------------------------------------------- launcher
extern "C" void kernel_launch(void* const* d_in, const int* in_sizes, int n_in,
                              void* d_out, int out_size, void* d_ws, size_t ws_size,
                              hipStream_t stream) {
  const float* x        = (const float*)d_in[0];
  const int*   senders  = (const int*)d_in[1];
  const int*   receivers= (const int*)d_in[2];
  const float* W1       = (const float*)d_in[3];
  const float* b1       = (const float*)d_in[4];
  const float* gamma    = (const float*)d_in[5];
  const float* beta     = (const float*)d_in[6];
  const float* bn_mean  = (const float*)d_in[7];
  const float* bn_var   = (const float*)d_in[8];
  const float* W_d1     = (const float*)d_in[9];
  const float* b_d1     = (const float*)d_in[10];
  const float* W_d2     = (const float*)d_in[11];
  const float* b_d2     = (const float*)d_in[12];
  const float* W_d3     = (const float*)d_in[13];
  const float* b_d3     = (const float*)d_in[14];
  float* out = (float*)d_out;

  // workspace layout (all 16B aligned)
  char* ws = (char*)d_ws;
  float* h      = (float*)ws;                       ws += (size_t)N_NODES * 64 * 4;   // 104,857,600
  int*   cnt    = (int*)ws;                         ws += (size_t)N_NODES * 4;        // 1,638,400
  int*   off    = (int*)ws;                         ws += (size_t)N_NODES * 4;
  int*   cur    = (int*)ws;                         ws += (size_t)N_NODES * 4;
  int*   sorted = (int*)ws;                         ws += (size_t)N_EDGES * 4;        // 26,214,400
  int*   bsum   = (int*)ws;                         ws += 2048 * 4;
  float* out1   = (float*)ws;                       ws += (size_t)N_GRAPHS * 256 * 4; // 4,194,304

  const int NBLK_NODES = N_NODES / 256;   // 1600
  const int NBLK_EDGES = N_EDGES / 256;   // 25600

  zero_kernel<<<NBLK_NODES, 256, 0, stream>>>(cnt, N_NODES);
  hist_kernel<<<NBLK_EDGES, 256, 0, stream>>>(receivers, cnt);
  scan1_kernel<<<NBLK_NODES, 256, 0, stream>>>(cnt, off, bsum);
  scan2_kernel<<<1, 256, 0, stream>>>(bsum, NBLK_NODES);
  scan3_kernel<<<NBLK_NODES, 256, 0, stream>>>(off, bsum, cur);
  scatter_kernel<<<NBLK_EDGES, 256, 0, stream>>>(receivers, senders, cur, sorted);
  aggconv_kernel<<<N_NODES / 4, 256, 0, stream>>>(x, off, cnt, sorted, W1, b1,
                                                  gamma, beta, bn_mean, bn_var, h);
  gemm2_kernel<<<dim3(N_GRAPHS / 64, 4), 256, 0, stream>>>(h, W_d1, b_d1, out1);
  tail_kernel<<<N_GRAPHS / 4, 256, 0, stream>>>(out1, W_d2, b_d2, W_d3, b_d3, out);
}